// Round 17
// baseline (2867.740 us; speedup 1.0000x reference)
//
#include <hip/hip_runtime.h>
#include <math.h>

constexpr int T_STEPS = 32;
constexpr int BATCH   = 128;
constexpr int IN_SZ   = 2048;   // K
constexpr int OUT_SZ  = 2048;   // N

// -------------------------------------------------------------------------
// FROZEN reference arithmetic (verified r14, absmax 0.0 in r15/r16):
//   GEMM: f32, KC=512 uniform K-blocks; per element a fresh ascending-k
//         fmaf chain per block, f32 sequential block-combine.
//   Scan: f64 state, un = D*u + y (sep mul/add), s = (un>=1), u = un-s,
//         D = 1/(1+exp(-2)) in f64.
// r17 optimization: 256x128 tile (32t x 8b x 128o), 512 threads, 8x8 micro
// (64 FMA : 4 ds_read_b128 per k), double-buffered LDS staging with register
// prefetch (ONE barrier per K-step, load latency hidden under compute).
// LDS 57.6 KB: buffer-1 aliased with the epilogue y-transpose buffer.
// Grid = 256 blocks = exactly 1 per CU. Per-element chain arithmetic is
// bit-identical to r15/r16.
// -------------------------------------------------------------------------
__global__ __launch_bounds__(512, 1) void Approx_OTPE_67181878444197_kernel(
        const float* __restrict__ x,
        const float* __restrict__ W,
        float* __restrict__ out) {
    constexpr int BK = 16, BM = 256, BN = 128, BB = 8;
    constexpr int ASZ  = BK * BM;          // 4096 floats
    constexpr int BSZ  = BK * BN;          // 2048 floats
    constexpr int BUF  = ASZ + BSZ;        // 6144 floats per stage buffer
    constexpr int YSTR = BN + 1;           // 129
    constexpr int YSZ  = 64 * YSTR;        // 8256 floats (> BUF)

    __shared__ float smem[BUF + YSZ];      // 14400 f = 57.6 KB
    // buffer 0: [0, BUF); buffer 1: [BUF, BUF+BUF) — aliased with y-buffer
    float* const yS = smem + BUF;

    const int o0  = blockIdx.x * BN;
    const int b0  = blockIdx.y * BB;
    const int tid = threadIdx.x;           // 0..511
    const int ty  = tid >> 4;              // 0..31 -> 8-row group
    const int tx  = tid & 15;              // 0..15 -> 8-col group

    // A staging: row am (0..255), k-half ak (0 or 8). m_local = t*8 + bl.
    const int am = tid >> 1;
    const int ak = (tid & 1) * 8;
    const int at = am >> 3;
    const int ab = am & 7;
    const size_t aBase = ((size_t)at * BATCH + (size_t)(b0 + ab)) * IN_SZ + ak;

    // B staging: row br (0..15), col bc (0..124), float4
    const int br = tid >> 5;
    const int bc = (tid & 31) * 4;

    float acc[8][8] = {};   // current KC=512 chain
    float su[8][8]  = {};   // running sequential block-combine

    // ---- prologue: stage K-step 0 into buffer 0 -------------------------
    {
        const float4 a0 = *reinterpret_cast<const float4*>(&x[aBase + 0]);
        const float4 a1 = *reinterpret_cast<const float4*>(&x[aBase + 4]);
        const float4 b  = *reinterpret_cast<const float4*>(
            &W[(size_t)br * OUT_SZ + o0 + bc]);
        float* const A0 = smem;            // As[0]
        float* const B0 = smem + ASZ;      // Bs[0]
        A0[(ak + 0) * BM + am] = a0.x;
        A0[(ak + 1) * BM + am] = a0.y;
        A0[(ak + 2) * BM + am] = a0.z;
        A0[(ak + 3) * BM + am] = a0.w;
        A0[(ak + 4) * BM + am] = a1.x;
        A0[(ak + 5) * BM + am] = a1.y;
        A0[(ak + 6) * BM + am] = a1.z;
        A0[(ak + 7) * BM + am] = a1.w;
        *reinterpret_cast<float4*>(&B0[br * BN + bc]) = b;
    }
    __syncthreads();

    // ---- main loop: one barrier per K-step, dbuf + reg prefetch ---------
    for (int it = 0; it < IN_SZ / BK; ++it) {
        const float* const Ac = (it & 1) ? (smem + BUF) : smem;
        const float* const Bc = Ac + ASZ;
        float* const An = (it & 1) ? smem : (smem + BUF);
        float* const Bn = An + ASZ;

        // prefetch next K-step into registers (latency hides under compute)
        float4 pa0, pa1, pb;
        const bool pre = (it < IN_SZ / BK - 1);
        if (pre) {
            const int k0n = (it + 1) * BK;
            pa0 = *reinterpret_cast<const float4*>(&x[aBase + k0n]);
            pa1 = *reinterpret_cast<const float4*>(&x[aBase + k0n + 4]);
            pb  = *reinterpret_cast<const float4*>(
                &W[(size_t)(k0n + br) * OUT_SZ + o0 + bc]);
        }

        // KC=512 boundary (k0 = 512/1024/1536): sequential combine
        if (it == 32 || it == 64 || it == 96) {
            #pragma unroll
            for (int i = 0; i < 8; ++i)
                #pragma unroll
                for (int j = 0; j < 8; ++j) {
                    su[i][j]  = __fadd_rn(su[i][j], acc[i][j]);
                    acc[i][j] = 0.0f;
                }
        }

        // ascending k; each acc[i][j] is one strict fmaf chain
        #pragma unroll
        for (int k = 0; k < BK; ++k) {
            const float4 x0 = *reinterpret_cast<const float4*>(&Ac[k * BM + ty * 8]);
            const float4 x1 = *reinterpret_cast<const float4*>(&Ac[k * BM + ty * 8 + 4]);
            const float4 w0 = *reinterpret_cast<const float4*>(&Bc[k * BN + tx * 8]);
            const float4 w1 = *reinterpret_cast<const float4*>(&Bc[k * BN + tx * 8 + 4]);
            const float a[8] = {x0.x, x0.y, x0.z, x0.w, x1.x, x1.y, x1.z, x1.w};
            const float w[8] = {w0.x, w0.y, w0.z, w0.w, w1.x, w1.y, w1.z, w1.w};
            #pragma unroll
            for (int i = 0; i < 8; ++i)
                #pragma unroll
                for (int j = 0; j < 8; ++j)
                    acc[i][j] = __builtin_fmaf(a[i], w[j], acc[i][j]);
        }

        // write prefetched data into the other buffer
        if (pre) {
            An[(ak + 0) * BM + am] = pa0.x;
            An[(ak + 1) * BM + am] = pa0.y;
            An[(ak + 2) * BM + am] = pa0.z;
            An[(ak + 3) * BM + am] = pa0.w;
            An[(ak + 4) * BM + am] = pa1.x;
            An[(ak + 5) * BM + am] = pa1.y;
            An[(ak + 6) * BM + am] = pa1.z;
            An[(ak + 7) * BM + am] = pa1.w;
            *reinterpret_cast<float4*>(&Bn[br * BN + bc]) = pb;
        }
        __syncthreads();
    }

    // final combine (frozen): y = su + acc, reusing su
    #pragma unroll
    for (int i = 0; i < 8; ++i)
        #pragma unroll
        for (int j = 0; j < 8; ++j)
            su[i][j] = __fadd_rn(su[i][j], acc[i][j]);

    // ---- fused f64 scan: 4 phases of 8 timesteps ------------------------
    const int sbl = tid >> 7;              // 0..3 (pairs with sbl+4)
    const int so  = tid & 127;             // 0..127
    const size_t plane = (size_t)BATCH * OUT_SZ;
    const size_t oi0 = (size_t)(b0 + sbl)     * OUT_SZ + o0 + so;
    const size_t oi1 = (size_t)(b0 + sbl + 4) * OUT_SZ + o0 + so;
    const double D = 1.0 / (1.0 + exp(-2.0));
    double u0 = 0.0, u1 = 0.0;
    const int myp = ty >> 3;               // wave-uniform phase ownership

    for (int p = 0; p < 4; ++p) {
        __syncthreads();                   // prev phase reads done
        if (myp == p) {
            const int rb = (ty - p * 8) * 8;
            #pragma unroll
            for (int i = 0; i < 8; ++i)
                #pragma unroll
                for (int j = 0; j < 8; ++j)
                    yS[(rb + i) * YSTR + tx * 8 + j] = su[i][j];
        }
        __syncthreads();
        #pragma unroll
        for (int tt = 0; tt < 8; ++tt) {
            const int t = p * 8 + tt;
            const double y0 = (double)yS[(tt * 8 + sbl) * YSTR + so];
            const double n0 = __dadd_rn(__dmul_rn(D, u0), y0);
            const double s0 = (n0 >= 1.0) ? 1.0 : 0.0;
            u0 = __dsub_rn(n0, s0);
            out[(size_t)t * plane + oi0] = (float)s0;

            const double y1 = (double)yS[(tt * 8 + sbl + 4) * YSTR + so];
            const double n1 = __dadd_rn(__dmul_rn(D, u1), y1);
            const double s1 = (n1 >= 1.0) ? 1.0 : 0.0;
            u1 = __dsub_rn(n1, s1);
            out[(size_t)t * plane + oi1] = (float)s1;
        }
    }
}

// -------------------------------------------------------------------------
extern "C" void kernel_launch(void* const* d_in, const int* in_sizes, int n_in,
                              void* d_out, int out_size, void* d_ws, size_t ws_size,
                              hipStream_t stream) {
    const float* x = (const float*)d_in[0];   // [T, B, IN] f32
    const float* W = (const float*)d_in[1];   // [IN, OUT] f32
    float* out     = (float*)d_out;           // [T, B, OUT] f32 spikes

    dim3 grid(OUT_SZ / 128, BATCH / 8);       // 16 x 16 = 256 blocks (1/CU)
    Approx_OTPE_67181878444197_kernel<<<grid, 512, 0, stream>>>(x, W, out);
}

// Round 18
// 569.502 us; speedup vs baseline: 5.0355x; 5.0355x over previous
//
#include <hip/hip_runtime.h>
#include <math.h>

constexpr int T_STEPS = 32;
constexpr int BATCH   = 128;
constexpr int IN_SZ   = 2048;   // K
constexpr int OUT_SZ  = 2048;   // N

// -------------------------------------------------------------------------
// FROZEN reference arithmetic (verified r14, absmax 0.0 in r15/r16):
//   GEMM: f32, KC=512 uniform K-blocks; per element a fresh ascending-k
//         fmaf chain per block, f32 sequential block-combine.
//   Scan: f64 state, un = D*u + y (sep mul/add), s = (un>=1), u = un-s,
//         D = 1/(1+exp(-2)) in f64.
// r18: r16's 128x64 tile + 8x4 micro (64 accum regs, NO spill -- r17's
// 8x8 spilled 12 GB of scratch) combined with r17's double-buffered
// one-barrier K-loop + register prefetch. Staging patterns = r16
// (conflict-free). LDS 33.3 KB (y-buffer aliases the two stage buffers)
// -> 4 blocks/CU, 16 waves/CU. Per-element arithmetic bit-identical.
// -------------------------------------------------------------------------
__global__ __launch_bounds__(256, 1) void Approx_OTPE_67181878444197_kernel(
        const float* __restrict__ x,
        const float* __restrict__ W,
        float* __restrict__ out) {
    constexpr int BK = 16, BM = 128, BN = 64, BB = 4;
    constexpr int ASZ  = BK * BM;          // 2048 floats
    constexpr int BSZ  = BK * BN;          // 1024 floats
    constexpr int BUF  = ASZ + BSZ;        // 3072 floats per stage buffer
    constexpr int YSTR = BN + 1;           // 65
    constexpr int YSZ  = BM * YSTR;        // 8320 floats = 33.3 KB

    __shared__ float smem[YSZ];            // y-buffer aliases both stage bufs

    const int o0  = blockIdx.x * BN;
    const int b0  = blockIdx.y * BB;
    const int tid = threadIdx.x;           // 0..255
    const int ty  = tid >> 4;              // 0..15 -> 8-row group
    const int tx  = tid & 15;              // 0..15 -> 4-col group

    // A staging: m_local = tid>>1 (0..127), k-half = (tid&1)*8
    // m_local = t*4 + bl  ->  global row t*BATCH + (b0+bl)
    const int am = tid >> 1;
    const int ak = (tid & 1) * 8;
    const int at = am >> 2;
    const int ab = am & 3;
    const size_t aBase = ((size_t)at * BATCH + (size_t)(b0 + ab)) * IN_SZ + ak;

    // B staging: row br (0..15), col bc (0..60), float4
    const int br = tid >> 4;
    const int bc = (tid & 15) * 4;

    float acc[8][4] = {};   // current KC=512 chain
    float su[8][4]  = {};   // running sequential block-combine

    // ---- prologue: stage K-step 0 into buffer 0 -------------------------
    {
        const float4 a0 = *reinterpret_cast<const float4*>(&x[aBase + 0]);
        const float4 a1 = *reinterpret_cast<const float4*>(&x[aBase + 4]);
        const float4 b  = *reinterpret_cast<const float4*>(
            &W[(size_t)br * OUT_SZ + o0 + bc]);
        float* const A0 = smem;
        float* const B0 = smem + ASZ;
        A0[(ak + 0) * BM + am] = a0.x;
        A0[(ak + 1) * BM + am] = a0.y;
        A0[(ak + 2) * BM + am] = a0.z;
        A0[(ak + 3) * BM + am] = a0.w;
        A0[(ak + 4) * BM + am] = a1.x;
        A0[(ak + 5) * BM + am] = a1.y;
        A0[(ak + 6) * BM + am] = a1.z;
        A0[(ak + 7) * BM + am] = a1.w;
        *reinterpret_cast<float4*>(&B0[br * BN + bc]) = b;
    }
    __syncthreads();

    // ---- main loop: one barrier per K-step, dbuf + register prefetch ----
    for (int it = 0; it < IN_SZ / BK; ++it) {
        const float* const Ac = (it & 1) ? (smem + BUF) : smem;
        const float* const Bc = Ac + ASZ;
        float* const An = (it & 1) ? smem : (smem + BUF);
        float* const Bn = An + ASZ;

        // prefetch next K-step into registers (hides under compute)
        float4 pa0, pa1, pb;
        const bool pre = (it < IN_SZ / BK - 1);
        if (pre) {
            const int k0n = (it + 1) * BK;
            pa0 = *reinterpret_cast<const float4*>(&x[aBase + k0n]);
            pa1 = *reinterpret_cast<const float4*>(&x[aBase + k0n + 4]);
            pb  = *reinterpret_cast<const float4*>(
                &W[(size_t)(k0n + br) * OUT_SZ + o0 + bc]);
        }

        // KC=512 boundary (k0 = 512/1024/1536): sequential combine
        if (it == 32 || it == 64 || it == 96) {
            #pragma unroll
            for (int i = 0; i < 8; ++i)
                #pragma unroll
                for (int j = 0; j < 4; ++j) {
                    su[i][j]  = __fadd_rn(su[i][j], acc[i][j]);
                    acc[i][j] = 0.0f;
                }
        }

        // ascending k; each acc[i][j] is one strict fmaf chain
        #pragma unroll
        for (int k = 0; k < BK; ++k) {
            const float4 x0 = *reinterpret_cast<const float4*>(&Ac[k * BM + ty * 8]);
            const float4 x1 = *reinterpret_cast<const float4*>(&Ac[k * BM + ty * 8 + 4]);
            const float4 wf = *reinterpret_cast<const float4*>(&Bc[k * BN + tx * 4]);
            const float a[8] = {x0.x, x0.y, x0.z, x0.w, x1.x, x1.y, x1.z, x1.w};
            const float w[4] = {wf.x, wf.y, wf.z, wf.w};
            #pragma unroll
            for (int i = 0; i < 8; ++i)
                #pragma unroll
                for (int j = 0; j < 4; ++j)
                    acc[i][j] = __builtin_fmaf(a[i], w[j], acc[i][j]);
        }

        // write prefetched data into the other buffer
        if (pre) {
            An[(ak + 0) * BM + am] = pa0.x;
            An[(ak + 1) * BM + am] = pa0.y;
            An[(ak + 2) * BM + am] = pa0.z;
            An[(ak + 3) * BM + am] = pa0.w;
            An[(ak + 4) * BM + am] = pa1.x;
            An[(ak + 5) * BM + am] = pa1.y;
            An[(ak + 6) * BM + am] = pa1.z;
            An[(ak + 7) * BM + am] = pa1.w;
            *reinterpret_cast<float4*>(&Bn[br * BN + bc]) = pb;
        }
        __syncthreads();
    }

    // final combine (frozen) + y-transpose dump (staging region is dead)
    #pragma unroll
    for (int i = 0; i < 8; ++i)
        #pragma unroll
        for (int j = 0; j < 4; ++j)
            smem[(ty * 8 + i) * YSTR + tx * 4 + j] = __fadd_rn(su[i][j], acc[i][j]);
    __syncthreads();

    // fused f64 scan: all 256 threads, one (bl, o) pair each
    {
        const int bl = tid >> 6;            // 0..3
        const int o  = tid & 63;            // 0..63
        const size_t plane  = (size_t)BATCH * OUT_SZ;
        const size_t outIdx = (size_t)(b0 + bl) * OUT_SZ + o0 + o;

        const double D = 1.0 / (1.0 + exp(-2.0));
        double u = 0.0;
        #pragma unroll
        for (int t = 0; t < T_STEPS; ++t) {
            const double y  = (double)smem[(t * 4 + bl) * YSTR + o];
            const double un = __dadd_rn(__dmul_rn(D, u), y);
            const double s  = (un >= 1.0) ? 1.0 : 0.0;
            u = __dsub_rn(un, s);
            out[(size_t)t * plane + outIdx] = (float)s;
        }
    }
}

// -------------------------------------------------------------------------
extern "C" void kernel_launch(void* const* d_in, const int* in_sizes, int n_in,
                              void* d_out, int out_size, void* d_ws, size_t ws_size,
                              hipStream_t stream) {
    const float* x = (const float*)d_in[0];   // [T, B, IN] f32
    const float* W = (const float*)d_in[1];   // [IN, OUT] f32
    float* out     = (float*)d_out;           // [T, B, OUT] f32 spikes

    dim3 grid(OUT_SZ / 64, BATCH / 4);        // 32 x 32 = 1024 blocks (4/CU)
    Approx_OTPE_67181878444197_kernel<<<grid, 256, 0, stream>>>(x, W, out);
}

// Round 19
// 477.342 us; speedup vs baseline: 6.0077x; 1.1931x over previous
//
#include <hip/hip_runtime.h>
#include <math.h>
#include <stdint.h>

constexpr int T_STEPS = 32;
constexpr int BATCH   = 128;
constexpr int IN_SZ   = 2048;   // K
constexpr int OUT_SZ  = 2048;   // N

// -------------------------------------------------------------------------
// FROZEN reference arithmetic (verified r14, absmax 0.0 r15/r16/r17/r18):
//   GEMM: f32, KC=512 uniform K-blocks; per element a fresh ascending-k
//         fmaf chain per block, f32 sequential block-combine.
//   Scan: f64 state, un = D*u + y (sep mul/add), s = (un>=1), u = un-s,
//         D = 1/(1+exp(-2)) in f64.
// r19: r16's 128x64 tile + 8x4 micro (64 accum regs) with an m97-style
// async pipeline: B-tile staged via global_load_lds (16B/lane, ZERO VGPRs,
// lane-linear LDS dest), A-tile reg-prefetched (8 VGPRs), double-buffered,
// ONE __syncthreads per K-step (its implicit vmcnt(0) drains the DMA).
// LDS 33.3 KB (y-buffer aliases both stage buffers) -> 4 blocks/CU.
// Per-element chain arithmetic bit-identical to r15-r18.
// -------------------------------------------------------------------------

__device__ __forceinline__ void async_lds16(const float* gsrc, float* lds_dst) {
    // global -> LDS 16B DMA; lds_dst must be wave-uniform (lane offset is HW)
    __builtin_amdgcn_global_load_lds(
        (const __attribute__((address_space(1))) uint32_t*)(uintptr_t)gsrc,
        (__attribute__((address_space(3))) uint32_t*)(uint32_t)(uintptr_t)lds_dst,
        16, 0, 0);
}

__global__ __launch_bounds__(256, 4) void Approx_OTPE_67181878444197_kernel(
        const float* __restrict__ x,
        const float* __restrict__ W,
        float* __restrict__ out) {
    constexpr int BK = 16, BM = 128, BN = 64, BB = 4;
    constexpr int ASZ  = BK * BM;          // 2048 floats
    constexpr int BSZ  = BK * BN;          // 1024 floats
    constexpr int BUF  = ASZ + BSZ;        // 3072 floats per stage buffer
    constexpr int YSTR = BN + 1;           // 65
    constexpr int YSZ  = BM * YSTR;        // 8320 floats = 33.3 KB
    constexpr int NIT  = IN_SZ / BK;       // 128

    __shared__ float smem[YSZ];            // y-buffer aliases both stage bufs

    const int o0  = blockIdx.x * BN;
    const int b0  = blockIdx.y * BB;
    const int tid = threadIdx.x;           // 0..255
    const int ty  = tid >> 4;              // 0..15 -> 8-row group
    const int tx  = tid & 15;              // 0..15 -> 4-col group
    const int wv  = tid >> 6;              // wave id 0..3 (uniform per wave)

    // A staging: m_local = tid>>1 (0..127), k-half = (tid&1)*8
    // m_local = t*4 + bl  ->  global row t*BATCH + (b0+bl)
    const int am = tid >> 1;
    const int ak = (tid & 1) * 8;
    const int at = am >> 2;
    const int ab = am & 3;
    const size_t aBase = ((size_t)at * BATCH + (size_t)(b0 + ab)) * IN_SZ + ak;

    // B staging (async DMA): lane-linear [k][n] tile; row br, col bc
    const int br = tid >> 4;               // 0..15
    const int bc = (tid & 15) * 4;         // 0..60

    float acc[8][4] = {};   // current KC=512 chain
    float su[8][4]  = {};   // running sequential block-combine

    // ---- prologue: stage tile 0 into buffer 0 ---------------------------
    {
        float* const A0 = smem;
        float* const B0 = smem + ASZ;
        async_lds16(&W[(size_t)br * OUT_SZ + o0 + bc], B0 + wv * 256);
        const float4 a0 = *reinterpret_cast<const float4*>(&x[aBase + 0]);
        const float4 a1 = *reinterpret_cast<const float4*>(&x[aBase + 4]);
        A0[(ak + 0) * BM + am] = a0.x;
        A0[(ak + 1) * BM + am] = a0.y;
        A0[(ak + 2) * BM + am] = a0.z;
        A0[(ak + 3) * BM + am] = a0.w;
        A0[(ak + 4) * BM + am] = a1.x;
        A0[(ak + 5) * BM + am] = a1.y;
        A0[(ak + 6) * BM + am] = a1.z;
        A0[(ak + 7) * BM + am] = a1.w;
    }
    __syncthreads();   // drains the DMA (vmcnt 0) + A writes

    // ---- main loop: ONE barrier per K-step ------------------------------
    for (int it = 0; it < NIT; ++it) {
        const float* const Ac = smem + (it & 1) * BUF;
        const float* const Bc = Ac + ASZ;
        float* const An = smem + ((it + 1) & 1) * BUF;
        float* const Bn = An + ASZ;

        // issue next tile's staging FIRST: B as zero-reg DMA, A into regs
        float4 pa0, pa1;
        const bool pre = (it < NIT - 1);
        if (pre) {
            const int k0n = (it + 1) * BK;
            async_lds16(&W[(size_t)(k0n + br) * OUT_SZ + o0 + bc], Bn + wv * 256);
            pa0 = *reinterpret_cast<const float4*>(&x[aBase + k0n]);
            pa1 = *reinterpret_cast<const float4*>(&x[aBase + k0n + 4]);
        }

        // KC=512 boundary (k0 = 512/1024/1536): sequential combine
        if (it == 32 || it == 64 || it == 96) {
            #pragma unroll
            for (int i = 0; i < 8; ++i)
                #pragma unroll
                for (int j = 0; j < 4; ++j) {
                    su[i][j]  = __fadd_rn(su[i][j], acc[i][j]);
                    acc[i][j] = 0.0f;
                }
        }

        // ascending k; each acc[i][j] is one strict fmaf chain
        #pragma unroll
        for (int k = 0; k < BK; ++k) {
            const float4 x0 = *reinterpret_cast<const float4*>(&Ac[k * BM + ty * 8]);
            const float4 x1 = *reinterpret_cast<const float4*>(&Ac[k * BM + ty * 8 + 4]);
            const float4 wf = *reinterpret_cast<const float4*>(&Bc[k * BN + tx * 4]);
            const float a[8] = {x0.x, x0.y, x0.z, x0.w, x1.x, x1.y, x1.z, x1.w};
            const float w[4] = {wf.x, wf.y, wf.z, wf.w};
            #pragma unroll
            for (int i = 0; i < 8; ++i)
                #pragma unroll
                for (int j = 0; j < 4; ++j)
                    acc[i][j] = __builtin_fmaf(a[i], w[j], acc[i][j]);
        }

        // write prefetched A into the other buffer (latency was hidden)
        if (pre) {
            An[(ak + 0) * BM + am] = pa0.x;
            An[(ak + 1) * BM + am] = pa0.y;
            An[(ak + 2) * BM + am] = pa0.z;
            An[(ak + 3) * BM + am] = pa0.w;
            An[(ak + 4) * BM + am] = pa1.x;
            An[(ak + 5) * BM + am] = pa1.y;
            An[(ak + 6) * BM + am] = pa1.z;
            An[(ak + 7) * BM + am] = pa1.w;
        }
        __syncthreads();   // implicit vmcnt(0): next tile's DMA complete
    }

    // final combine (frozen) + y-transpose dump (staging region is dead)
    #pragma unroll
    for (int i = 0; i < 8; ++i)
        #pragma unroll
        for (int j = 0; j < 4; ++j)
            smem[(ty * 8 + i) * YSTR + tx * 4 + j] = __fadd_rn(su[i][j], acc[i][j]);
    __syncthreads();

    // fused f64 scan: all 256 threads, one (bl, o) pair each
    {
        const int bl = tid >> 6;            // 0..3
        const int o  = tid & 63;            // 0..63
        const size_t plane  = (size_t)BATCH * OUT_SZ;
        const size_t outIdx = (size_t)(b0 + bl) * OUT_SZ + o0 + o;

        const double D = 1.0 / (1.0 + exp(-2.0));
        double u = 0.0;
        #pragma unroll
        for (int t = 0; t < T_STEPS; ++t) {
            const double y  = (double)smem[(t * 4 + bl) * YSTR + o];
            const double un = __dadd_rn(__dmul_rn(D, u), y);
            const double s  = (un >= 1.0) ? 1.0 : 0.0;
            u = __dsub_rn(un, s);
            out[(size_t)t * plane + outIdx] = (float)s;
        }
    }
}

// -------------------------------------------------------------------------
extern "C" void kernel_launch(void* const* d_in, const int* in_sizes, int n_in,
                              void* d_out, int out_size, void* d_ws, size_t ws_size,
                              hipStream_t stream) {
    const float* x = (const float*)d_in[0];   // [T, B, IN] f32
    const float* W = (const float*)d_in[1];   // [IN, OUT] f32
    float* out     = (float*)d_out;           // [T, B, OUT] f32 spikes

    dim3 grid(OUT_SZ / 64, BATCH / 4);        // 32 x 32 = 1024 blocks (4/CU)
    Approx_OTPE_67181878444197_kernel<<<grid, 256, 0, stream>>>(x, W, out);
}